// Round 1
// baseline (2245.965 us; speedup 1.0000x reference)
//
#include <hip/hip_runtime.h>

#define NN 20000
#define NE 320000
#define EPN (NE + NN)   // edges + self loops = 340000
#define NH 4
#define NC 64
#define HC 256          // NH*NC
#define RP_STRIDE 20004
#define DEG_CAP 512

// ---------------- CSR build ----------------
__global__ void k_init_counts(int* __restrict__ cnt) {
  int i = blockIdx.x * blockDim.x + threadIdx.x;
  if (i < 4 * NN) cnt[i] = 1;   // self loop
}

__global__ void k_count(const int* __restrict__ d0, const int* __restrict__ d1,
                        const int* __restrict__ d2, const int* __restrict__ d3,
                        int* __restrict__ cnt) {
  int i = blockIdx.x * blockDim.x + threadIdx.x;
  if (i >= 4 * NE) return;
  int t = i / NE, e = i - t * NE;
  const int* d = t == 0 ? d0 : t == 1 ? d1 : t == 2 ? d2 : d3;
  atomicAdd(&cnt[t * NN + d[e]], 1);
}

__global__ void k_scan(const int* __restrict__ cnt, int* __restrict__ rp, int* __restrict__ tmp) {
  int t = blockIdx.x;
  const int* c = cnt + t * NN;
  int* r = rp + t * RP_STRIDE;
  int* tm = tmp + t * NN;
  __shared__ int part[256];
  int tid = threadIdx.x;
  const int CH = (NN + 255) / 256;
  int lo = tid * CH, hi = min(lo + CH, NN);
  int s = 0;
  for (int i = lo; i < hi; i++) s += c[i];
  part[tid] = s;
  __syncthreads();
  if (tid == 0) {
    int run = 0;
    for (int i = 0; i < 256; i++) { int v = part[i]; part[i] = run; run += v; }
  }
  __syncthreads();
  int run = part[tid];
  for (int i = lo; i < hi; i++) { r[i] = run; tm[i] = run; run += c[i]; }
  if (lo < NN && hi == NN) r[NN] = run;
}

__global__ void k_fill(const int* __restrict__ e0, const int* __restrict__ e1,
                       const int* __restrict__ e2, const int* __restrict__ e3,
                       int* __restrict__ tmp, int* __restrict__ col) {
  int i = blockIdx.x * blockDim.x + threadIdx.x;
  if (i >= 4 * EPN) return;
  int t = i / EPN, j = i - t * EPN;
  const int* eb = t == 0 ? e0 : t == 1 ? e1 : t == 2 ? e2 : e3;
  int s, d;
  if (j < NE) { s = eb[j]; d = eb[NE + j]; } else { s = d = j - NE; }
  int pos = atomicAdd(&tmp[t * NN + d], 1);
  col[(size_t)t * EPN + pos] = s;
}

// ---------------- GEMM: h[NN][256] = A[NN][K] @ B[K][256] ----------------
template <int K>
__global__ __launch_bounds__(256) void k_gemm(const float* __restrict__ A,
                                              const float* __restrict__ B,
                                              float* __restrict__ C) {
  __shared__ __align__(16) float As[64][68];  // [k][row]
  __shared__ __align__(16) float Bs[64][68];  // [k][col]
  int tid = threadIdx.x;
  int row0 = blockIdx.x * 64;
  int col0 = blockIdx.y * 64;
  int tx = tid & 15, ty = tid >> 4;
  float acc[4][4] = {};
  for (int kb = 0; kb < K; kb += 64) {
    for (int idx = tid; idx < 1024; idx += 256) {
      int r = idx >> 4;
      int kc = (idx & 15) << 2;
      int gr = row0 + r;
      float4 v = make_float4(0.f, 0.f, 0.f, 0.f);
      if (gr < NN) v = *(const float4*)(A + (size_t)gr * K + kb + kc);
      As[kc + 0][r] = v.x; As[kc + 1][r] = v.y; As[kc + 2][r] = v.z; As[kc + 3][r] = v.w;
    }
    for (int idx = tid; idx < 1024; idx += 256) {
      int r = idx >> 4;
      int cc = (idx & 15) << 2;
      *(float4*)&Bs[r][cc] = *(const float4*)(B + (size_t)(kb + r) * HC + col0 + cc);
    }
    __syncthreads();
#pragma unroll
    for (int k = 0; k < 64; k++) {
      float4 a = *(const float4*)&As[k][ty << 2];
      float4 b = *(const float4*)&Bs[k][tx << 2];
      float av[4] = {a.x, a.y, a.z, a.w};
      float bv[4] = {b.x, b.y, b.z, b.w};
#pragma unroll
      for (int i = 0; i < 4; i++)
#pragma unroll
        for (int j = 0; j < 4; j++) acc[i][j] = fmaf(av[i], bv[j], acc[i][j]);
    }
    __syncthreads();
  }
  for (int i = 0; i < 4; i++) {
    int gr = row0 + (ty << 2) + i;
    if (gr < NN) {
      float4 v = make_float4(acc[i][0], acc[i][1], acc[i][2], acc[i][3]);
      *(float4*)(C + (size_t)gr * HC + col0 + (tx << 2)) = v;
    }
  }
}

// ---------------- attention coefficients ----------------
__global__ __launch_bounds__(256) void k_attn(const float* __restrict__ h,
                                              const float* __restrict__ a_s,
                                              const float* __restrict__ a_d,
                                              float* __restrict__ asrc,
                                              float* __restrict__ adst) {
  int v = blockIdx.x;
  int tid = threadIdx.x;
  float hv = h[(size_t)v * HC + tid];
  float ps = hv * a_s[tid];
  float pd = hv * a_d[tid];
#pragma unroll
  for (int m = 32; m > 0; m >>= 1) {
    ps += __shfl_xor(ps, m);
    pd += __shfl_xor(pd, m);
  }
  if ((tid & 63) == 0) {
    int hd = tid >> 6;
    asrc[v * NH + hd] = ps;
    adst[v * NH + hd] = pd;
  }
}

// ---------------- per-node GAT aggregation (one block per dst node) ----------------
__global__ __launch_bounds__(256) void k_aggregate(const int* __restrict__ rp,
                                                   const int* __restrict__ col,
                                                   const float* __restrict__ asrc,
                                                   const float* __restrict__ adst,
                                                   const float* __restrict__ h,
                                                   const float* __restrict__ bvec,
                                                   float* __restrict__ accum) {
  __shared__ float wbuf[DEG_CAP * NH];
  __shared__ float red[256];
  __shared__ float mz[8];
  int v = blockIdx.x;
  int tid = threadIdx.x;
  int beg = rp[v];
  int deg = rp[v + 1] - beg;
  int hq = tid & 3;   // head for strided (edge,head) passes
  float adv = adst[v * NH + hq];

  // pass 1: segment max per head
  float mloc = -1e30f;
  for (int idx = tid; idx < deg * NH; idx += 256) {
    int i = idx >> 2;
    int s = col[beg + i];
    float e = asrc[s * NH + hq] + adv;
    e = e > 0.f ? e : 0.2f * e;
    mloc = fmaxf(mloc, e);
  }
  red[tid] = mloc;
  __syncthreads();
#pragma unroll
  for (int st = 128; st >= 4; st >>= 1) {
    if (tid < st) red[tid] = fmaxf(red[tid], red[tid + st]);
    __syncthreads();
  }
  if (tid < 4) mz[tid] = red[tid];
  __syncthreads();
  float mh = mz[hq];

  // pass 2/3 (chunked): w = exp(e-m) once per (edge,head); accumulate w*h[src]
  int hd = tid >> 6;
  float facc = 0.f;
  float zloc = 0.f;
  for (int cb = 0; cb < deg; cb += DEG_CAP) {
    int cn = min(DEG_CAP, deg - cb);
    __syncthreads();
    for (int idx = tid; idx < cn * NH; idx += 256) {
      int i = idx >> 2;
      int s = col[beg + cb + i];
      float e = asrc[s * NH + hq] + adv;
      e = e > 0.f ? e : 0.2f * e;
      float w = expf(e - mh);
      wbuf[idx] = w;
      zloc += w;
    }
    __syncthreads();
    for (int i = 0; i < cn; i++) {
      int s = col[beg + cb + i];
      facc = fmaf(wbuf[i * NH + hd], h[(size_t)s * HC + tid], facc);
    }
  }
  __syncthreads();
  red[tid] = zloc;
  __syncthreads();
#pragma unroll
  for (int st = 128; st >= 4; st >>= 1) {
    if (tid < st) red[tid] += red[tid + st];
    __syncthreads();
  }
  if (tid < 4) mz[4 + tid] = red[tid];
  __syncthreads();
  float r = facc / mz[4 + hd];
  red[tid] = r;
  __syncthreads();
  if (tid < 64) {
    float s4 = (red[tid] + red[tid + 64] + red[tid + 128] + red[tid + 192]) * 0.25f + bvec[tid];
    accum[v * NC + tid] += s4;
  }
}

__global__ void k_finalize(const float* __restrict__ accum, float* __restrict__ xout) {
  int i = blockIdx.x * blockDim.x + threadIdx.x;
  if (i < NN * NC) xout[i] = fmaxf(accum[i] * 0.25f, 0.f);
}

__global__ void k_linear(const float* __restrict__ x, const float* __restrict__ W,
                         const float* __restrict__ b, float* __restrict__ out) {
  int i = blockIdx.x * blockDim.x + threadIdx.x;
  if (i >= NN * 32) return;
  int v = i >> 5, o = i & 31;
  float acc = b[o];
#pragma unroll
  for (int c = 0; c < 64; c++) acc = fmaf(x[v * 64 + c], W[c * 32 + o], acc);
  out[i] = acc;
}

extern "C" void kernel_launch(void* const* d_in, const int* in_sizes, int n_in,
                              void* d_out, int out_size, void* d_ws, size_t ws_size,
                              hipStream_t stream) {
  const float* x = (const float*)d_in[0];
  const int* e0 = (const int*)d_in[1];
  const int* e1 = (const int*)d_in[2];
  const int* e2 = (const int*)d_in[3];
  const int* e3 = (const int*)d_in[4];
  const float* Wl[2]  = {(const float*)d_in[5], (const float*)d_in[9]};
  const float* asl[2] = {(const float*)d_in[6], (const float*)d_in[10]};
  const float* adl[2] = {(const float*)d_in[7], (const float*)d_in[11]};
  const float* bl[2]  = {(const float*)d_in[8], (const float*)d_in[12]};
  const float* linW = (const float*)d_in[13];
  const float* linb = (const float*)d_in[14];
  float* out = (float*)d_out;
  (void)in_sizes; (void)n_in; (void)out_size; (void)ws_size;

  char* wsb = (char*)d_ws;
  size_t off = 0;
  auto carve = [&](size_t bytes) -> char* {
    off = (off + 255) & ~(size_t)255;
    char* p = wsb + off;
    off += bytes;
    return p;
  };
  int* cnt    = (int*)carve((size_t)4 * NN * sizeof(int));
  int* tmp    = (int*)carve((size_t)4 * NN * sizeof(int));
  int* rp     = (int*)carve((size_t)4 * RP_STRIDE * sizeof(int));
  int* col    = (int*)carve((size_t)4 * EPN * sizeof(int));
  float* asrc = (float*)carve((size_t)NN * NH * sizeof(float));
  float* adst = (float*)carve((size_t)NN * NH * sizeof(float));
  float* h    = (float*)carve((size_t)NN * HC * sizeof(float));
  float* accum= (float*)carve((size_t)NN * NC * sizeof(float));
  float* xmid = (float*)carve((size_t)NN * NC * sizeof(float));

  // CSR build (edges identical across layers -> build once)
  k_init_counts<<<(4 * NN + 255) / 256, 256, 0, stream>>>(cnt);
  k_count<<<(4 * NE + 255) / 256, 256, 0, stream>>>(e0 + NE, e1 + NE, e2 + NE, e3 + NE, cnt);
  k_scan<<<4, 256, 0, stream>>>(cnt, rp, tmp);
  k_fill<<<(4 * EPN + 255) / 256, 256, 0, stream>>>(e0, e1, e2, e3, tmp, col);

  for (int l = 0; l < 2; l++) {
    const float* xin = (l == 0) ? x : xmid;
    hipMemsetAsync(accum, 0, (size_t)NN * NC * sizeof(float), stream);
    for (int t = 0; t < 4; t++) {
      if (l == 0)
        k_gemm<128><<<dim3((NN + 63) / 64, 4), 256, 0, stream>>>(
            xin, Wl[l] + (size_t)t * 128 * HC, h);
      else
        k_gemm<64><<<dim3((NN + 63) / 64, 4), 256, 0, stream>>>(
            xin, Wl[l] + (size_t)t * 64 * HC, h);
      k_attn<<<NN, 256, 0, stream>>>(h, asl[l] + t * HC, adl[l] + t * HC, asrc, adst);
      k_aggregate<<<NN, 256, 0, stream>>>(rp + t * RP_STRIDE, col + (size_t)t * EPN,
                                          asrc, adst, h, bl[l] + t * NC, accum);
    }
    k_finalize<<<(NN * NC + 255) / 256, 256, 0, stream>>>(accum, xmid);
  }
  k_linear<<<(NN * 32 + 255) / 256, 256, 0, stream>>>(xmid, linW, linb, out);
}

// Round 2
// 827.228 us; speedup vs baseline: 2.7151x; 2.7151x over previous
//
#include <hip/hip_runtime.h>

#define NN 20000
#define NE 320000
#define EPN (NE + NN)   // edges + self loops = 340000
#define NH 4
#define NC 64
#define RP_STRIDE 20004
#define DEG_CAP 512

// ---------------- CSR build ----------------
__global__ void k_init_counts(int* __restrict__ cnt) {
  int i = blockIdx.x * blockDim.x + threadIdx.x;
  if (i < 4 * NN) cnt[i] = 1;   // self loop
}

__global__ void k_count(const int* __restrict__ d0, const int* __restrict__ d1,
                        const int* __restrict__ d2, const int* __restrict__ d3,
                        int* __restrict__ cnt) {
  int i = blockIdx.x * blockDim.x + threadIdx.x;
  if (i >= 4 * NE) return;
  int t = i / NE, e = i - t * NE;
  const int* d = t == 0 ? d0 : t == 1 ? d1 : t == 2 ? d2 : d3;
  atomicAdd(&cnt[t * NN + d[e]], 1);
}

__global__ void k_scan(const int* __restrict__ cnt, int* __restrict__ rp, int* __restrict__ tmp) {
  int t = blockIdx.x;
  const int* c = cnt + t * NN;
  int* r = rp + t * RP_STRIDE;
  int* tm = tmp + t * NN;
  __shared__ int part[256];
  int tid = threadIdx.x;
  const int CH = (NN + 255) / 256;
  int lo = tid * CH, hi = min(lo + CH, NN);
  int s = 0;
  for (int i = lo; i < hi; i++) s += c[i];
  part[tid] = s;
  __syncthreads();
  if (tid == 0) {
    int run = 0;
    for (int i = 0; i < 256; i++) { int v = part[i]; part[i] = run; run += v; }
  }
  __syncthreads();
  int run = part[tid];
  for (int i = lo; i < hi; i++) { r[i] = run; tm[i] = run; run += c[i]; }
  if (lo < NN && hi == NN) r[NN] = run;
}

__global__ void k_fill(const int* __restrict__ e0, const int* __restrict__ e1,
                       const int* __restrict__ e2, const int* __restrict__ e3,
                       int* __restrict__ tmp, int* __restrict__ col) {
  int i = blockIdx.x * blockDim.x + threadIdx.x;
  if (i >= 4 * EPN) return;
  int t = i / EPN, j = i - t * EPN;
  const int* eb = t == 0 ? e0 : t == 1 ? e1 : t == 2 ? e2 : e3;
  int s, d;
  if (j < NE) { s = eb[j]; d = eb[NE + j]; } else { s = d = j - NE; }
  int pos = atomicAdd(&tmp[t * NN + d], 1);
  col[(size_t)t * EPN + pos] = s;
}

// ---------------- fused GEMM + attention-coefficient epilogue ----------------
// H[row][hcol] = A[row][:] @ W[t][:][wc+c], with per-(node,head) a_src/a_dst dots
// computed in the epilogue. colbase: global fused column of blockIdx.y==0
// (fused mode: 0, grid.y=8; per-type mode: t*256, grid.y=2).
template <int K>
__global__ __launch_bounds__(256, 2) void k_gemm_attn(
    const float* __restrict__ A, const float* __restrict__ W,
    const float* __restrict__ a_s, const float* __restrict__ a_d,
    float* __restrict__ H, float* __restrict__ asrc, float* __restrict__ adst,
    int colbase, int hstride) {
  __shared__ float As[64][33];    // [row][k]
  __shared__ float Bs[32][132];   // [k][col], padded
  int tid = threadIdx.x;
  int row0 = blockIdx.x << 6;
  int hcolb = blockIdx.y << 7;          // column within H
  int gc0 = colbase + hcolb;            // global fused column (0..1023)
  int t = gc0 >> 8, wc = gc0 & 255;
  const float* WB = W + (size_t)t * K * 256 + wc;
  int tx = tid & 15, ty = tid >> 4;     // tx: 8-col group, ty: 4-row group
  int r_a = tid >> 3, kc_a = (tid & 7) << 2;
  float acc[4][8] = {};

  for (int kb = 0; kb < K; kb += 32) {
    float4 av0 = make_float4(0.f, 0.f, 0.f, 0.f);
    float4 av1 = make_float4(0.f, 0.f, 0.f, 0.f);
    if (row0 + r_a < NN)
      av0 = *(const float4*)(A + (size_t)(row0 + r_a) * K + kb + kc_a);
    if (row0 + r_a + 32 < NN)
      av1 = *(const float4*)(A + (size_t)(row0 + r_a + 32) * K + kb + kc_a);
    float4 bv[4];
#pragma unroll
    for (int n = 0; n < 4; n++) {
      int idx = tid + (n << 8);
      int rb = idx >> 5, c4 = (idx & 31) << 2;
      bv[n] = *(const float4*)(WB + (size_t)(kb + rb) * 256 + c4);
    }
    __syncthreads();
    As[r_a][kc_a + 0] = av0.x; As[r_a][kc_a + 1] = av0.y;
    As[r_a][kc_a + 2] = av0.z; As[r_a][kc_a + 3] = av0.w;
    As[r_a + 32][kc_a + 0] = av1.x; As[r_a + 32][kc_a + 1] = av1.y;
    As[r_a + 32][kc_a + 2] = av1.z; As[r_a + 32][kc_a + 3] = av1.w;
#pragma unroll
    for (int n = 0; n < 4; n++) {
      int idx = tid + (n << 8);
      int rb = idx >> 5, c4 = (idx & 31) << 2;
      *(float4*)&Bs[rb][c4] = bv[n];
    }
    __syncthreads();
#pragma unroll 4
    for (int k = 0; k < 32; k++) {
      float aa[4];
#pragma unroll
      for (int i = 0; i < 4; i++) aa[i] = As[(ty << 2) + i][k];
      float4 b0 = *(const float4*)&Bs[k][tx << 3];
      float4 b1 = *(const float4*)&Bs[k][(tx << 3) + 4];
      float bb[8] = {b0.x, b0.y, b0.z, b0.w, b1.x, b1.y, b1.z, b1.w};
#pragma unroll
      for (int i = 0; i < 4; i++)
#pragma unroll
        for (int j = 0; j < 8; j++) acc[i][j] = fmaf(aa[i], bb[j], acc[i][j]);
    }
    __syncthreads();
  }

  // epilogue: write H and per-(node,head) attention dots
  float asr[8], adr[8];
#pragma unroll
  for (int j = 0; j < 8; j++) {
    asr[j] = a_s[gc0 + (tx << 3) + j];
    adr[j] = a_d[gc0 + (tx << 3) + j];
  }
  int hslot = (gc0 + (tx << 3)) >> 6;   // t*4 + head
#pragma unroll
  for (int i = 0; i < 4; i++) {
    int gr = row0 + (ty << 2) + i;
    float ps = 0.f, pd = 0.f;
#pragma unroll
    for (int j = 0; j < 8; j++) {
      ps = fmaf(acc[i][j], asr[j], ps);
      pd = fmaf(acc[i][j], adr[j], pd);
    }
    ps += __shfl_xor(ps, 1); ps += __shfl_xor(ps, 2); ps += __shfl_xor(ps, 4);
    pd += __shfl_xor(pd, 1); pd += __shfl_xor(pd, 2); pd += __shfl_xor(pd, 4);
    if (gr < NN) {
      *(float4*)(H + (size_t)gr * hstride + hcolb + (tx << 3)) =
          make_float4(acc[i][0], acc[i][1], acc[i][2], acc[i][3]);
      *(float4*)(H + (size_t)gr * hstride + hcolb + (tx << 3) + 4) =
          make_float4(acc[i][4], acc[i][5], acc[i][6], acc[i][7]);
      if ((tx & 7) == 0) {
        asrc[(size_t)gr * 16 + hslot] = ps;
        adst[(size_t)gr * 16 + hslot] = pd;
      }
    }
  }
}

// ---------------- per-node GAT aggregation (one block per dst node) ----------------
// asrc/adst pre-offset by t*4 (stride 16); h pre-offset by type (stride hstride).
__global__ __launch_bounds__(256) void k_aggregate(const int* __restrict__ rp,
                                                   const int* __restrict__ col,
                                                   const float* __restrict__ asrc,
                                                   const float* __restrict__ adst,
                                                   const float* __restrict__ h,
                                                   const float* __restrict__ bvec,
                                                   float* __restrict__ accum,
                                                   int hstride) {
  __shared__ float wbuf[DEG_CAP * NH];
  __shared__ float red[256];
  __shared__ float mz[8];
  int v = blockIdx.x;
  int tid = threadIdx.x;
  int beg = rp[v];
  int deg = rp[v + 1] - beg;
  int hq = tid & 3;
  float adv = adst[(size_t)v * 16 + hq];

  // pass 1: segment max per head
  float mloc = -1e30f;
  for (int idx = tid; idx < deg * NH; idx += 256) {
    int i = idx >> 2;
    int s = col[beg + i];
    float e = asrc[(size_t)s * 16 + hq] + adv;
    e = e > 0.f ? e : 0.2f * e;
    mloc = fmaxf(mloc, e);
  }
  red[tid] = mloc;
  __syncthreads();
#pragma unroll
  for (int st = 128; st >= 4; st >>= 1) {
    if (tid < st) red[tid] = fmaxf(red[tid], red[tid + st]);
    __syncthreads();
  }
  if (tid < 4) mz[tid] = red[tid];
  __syncthreads();
  float mh = mz[hq];

  // pass 2/3: w = exp(e-m) once per (edge,head); accumulate w*h[src]
  int hd = tid >> 6;
  float facc = 0.f;
  float zloc = 0.f;
  for (int cb = 0; cb < deg; cb += DEG_CAP) {
    int cn = min(DEG_CAP, deg - cb);
    __syncthreads();
    for (int idx = tid; idx < cn * NH; idx += 256) {
      int i = idx >> 2;
      int s = col[beg + cb + i];
      float e = asrc[(size_t)s * 16 + hq] + adv;
      e = e > 0.f ? e : 0.2f * e;
      float w = expf(e - mh);
      wbuf[idx] = w;
      zloc += w;
    }
    __syncthreads();
    for (int i = 0; i < cn; i++) {
      int s = col[beg + cb + i];
      facc = fmaf(wbuf[i * NH + hd], h[(size_t)s * hstride + tid], facc);
    }
  }
  __syncthreads();
  red[tid] = zloc;
  __syncthreads();
#pragma unroll
  for (int st = 128; st >= 4; st >>= 1) {
    if (tid < st) red[tid] += red[tid + st];
    __syncthreads();
  }
  if (tid < 4) mz[4 + tid] = red[tid];
  __syncthreads();
  float r = facc / mz[4 + hd];
  red[tid] = r;
  __syncthreads();
  if (tid < 64) {
    float s4 = (red[tid] + red[tid + 64] + red[tid + 128] + red[tid + 192]) * 0.25f + bvec[tid];
    accum[v * NC + tid] += s4;
  }
}

__global__ void k_finalize(const float* __restrict__ accum, float* __restrict__ xout) {
  int i = blockIdx.x * blockDim.x + threadIdx.x;
  if (i < NN * NC) xout[i] = fmaxf(accum[i] * 0.25f, 0.f);
}

__global__ void k_linear(const float* __restrict__ x, const float* __restrict__ W,
                         const float* __restrict__ b, float* __restrict__ out) {
  int i = blockIdx.x * blockDim.x + threadIdx.x;
  if (i >= NN * 32) return;
  int v = i >> 5, o = i & 31;
  float acc = b[o];
#pragma unroll
  for (int c = 0; c < 64; c++) acc = fmaf(x[v * 64 + c], W[c * 32 + o], acc);
  out[i] = acc;
}

extern "C" void kernel_launch(void* const* d_in, const int* in_sizes, int n_in,
                              void* d_out, int out_size, void* d_ws, size_t ws_size,
                              hipStream_t stream) {
  const float* x = (const float*)d_in[0];
  const int* e0 = (const int*)d_in[1];
  const int* e1 = (const int*)d_in[2];
  const int* e2 = (const int*)d_in[3];
  const int* e3 = (const int*)d_in[4];
  const float* Wl[2]  = {(const float*)d_in[5], (const float*)d_in[9]};
  const float* asl[2] = {(const float*)d_in[6], (const float*)d_in[10]};
  const float* adl[2] = {(const float*)d_in[7], (const float*)d_in[11]};
  const float* bl[2]  = {(const float*)d_in[8], (const float*)d_in[12]};
  const float* linW = (const float*)d_in[13];
  const float* linb = (const float*)d_in[14];
  float* out = (float*)d_out;
  (void)in_sizes; (void)n_in; (void)out_size;

  bool fused = ws_size >= (size_t)112 * 1024 * 1024;

  char* wsb = (char*)d_ws;
  size_t off = 0;
  auto carve = [&](size_t bytes) -> char* {
    off = (off + 255) & ~(size_t)255;
    char* p = wsb + off;
    off += bytes;
    return p;
  };
  int* cnt    = (int*)carve((size_t)4 * NN * sizeof(int));
  int* tmp    = (int*)carve((size_t)4 * NN * sizeof(int));
  int* rp     = (int*)carve((size_t)4 * RP_STRIDE * sizeof(int));
  int* col    = (int*)carve((size_t)4 * EPN * sizeof(int));
  float* asrc = (float*)carve((size_t)NN * 16 * sizeof(float));
  float* adst = (float*)carve((size_t)NN * 16 * sizeof(float));
  float* h    = (float*)carve((size_t)NN * (fused ? 1024 : 256) * sizeof(float));
  float* accum= (float*)carve((size_t)NN * NC * sizeof(float));
  float* xmid = (float*)carve((size_t)NN * NC * sizeof(float));

  // CSR build (edges identical across layers -> build once)
  k_init_counts<<<(4 * NN + 255) / 256, 256, 0, stream>>>(cnt);
  k_count<<<(4 * NE + 255) / 256, 256, 0, stream>>>(e0 + NE, e1 + NE, e2 + NE, e3 + NE, cnt);
  k_scan<<<4, 256, 0, stream>>>(cnt, rp, tmp);
  k_fill<<<(4 * EPN + 255) / 256, 256, 0, stream>>>(e0, e1, e2, e3, tmp, col);

  const int GBX = (NN + 63) / 64;
  for (int l = 0; l < 2; l++) {
    const float* xin = (l == 0) ? x : xmid;
    hipMemsetAsync(accum, 0, (size_t)NN * NC * sizeof(float), stream);
    if (fused) {
      if (l == 0)
        k_gemm_attn<128><<<dim3(GBX, 8), 256, 0, stream>>>(
            xin, Wl[l], asl[l], adl[l], h, asrc, adst, 0, 1024);
      else
        k_gemm_attn<64><<<dim3(GBX, 8), 256, 0, stream>>>(
            xin, Wl[l], asl[l], adl[l], h, asrc, adst, 0, 1024);
      for (int t = 0; t < 4; t++)
        k_aggregate<<<NN, 256, 0, stream>>>(rp + t * RP_STRIDE, col + (size_t)t * EPN,
                                            asrc + t * 4, adst + t * 4,
                                            h + t * 256, bl[l] + t * NC, accum, 1024);
    } else {
      for (int t = 0; t < 4; t++) {
        if (l == 0)
          k_gemm_attn<128><<<dim3(GBX, 2), 256, 0, stream>>>(
              xin, Wl[l], asl[l], adl[l], h, asrc, adst, t * 256, 256);
        else
          k_gemm_attn<64><<<dim3(GBX, 2), 256, 0, stream>>>(
              xin, Wl[l], asl[l], adl[l], h, asrc, adst, t * 256, 256);
        k_aggregate<<<NN, 256, 0, stream>>>(rp + t * RP_STRIDE, col + (size_t)t * EPN,
                                            asrc + t * 4, adst + t * 4,
                                            h, bl[l] + t * NC, accum, 256);
      }
    }
    k_finalize<<<(NN * NC + 255) / 256, 256, 0, stream>>>(accum, xmid);
  }
  k_linear<<<(NN * 32 + 255) / 256, 256, 0, stream>>>(xmid, linW, linb, out);
}

// Round 3
// 718.639 us; speedup vs baseline: 3.1253x; 1.1511x over previous
//
#include <hip/hip_runtime.h>

#define NN 20000
#define NE 320000
#define EPN (NE + NN)   // edges + self loops = 340000
#define NH 4
#define NC 64
#define RP_STRIDE 20004

// ---------------- CSR build ----------------
__global__ void k_init_counts(int* __restrict__ cnt) {
  int i = blockIdx.x * blockDim.x + threadIdx.x;
  if (i < 4 * NN) cnt[i] = 1;   // self loop
}

__global__ void k_count(const int* __restrict__ d0, const int* __restrict__ d1,
                        const int* __restrict__ d2, const int* __restrict__ d3,
                        int* __restrict__ cnt) {
  int i = blockIdx.x * blockDim.x + threadIdx.x;
  if (i >= 4 * NE) return;
  int t = i / NE, e = i - t * NE;
  const int* d = t == 0 ? d0 : t == 1 ? d1 : t == 2 ? d2 : d3;
  atomicAdd(&cnt[t * NN + d[e]], 1);
}

__global__ void k_scan(const int* __restrict__ cnt, int* __restrict__ rp, int* __restrict__ tmp) {
  int t = blockIdx.x;
  const int* c = cnt + t * NN;
  int* r = rp + t * RP_STRIDE;
  int* tm = tmp + t * NN;
  __shared__ int part[256];
  int tid = threadIdx.x;
  const int CH = (NN + 255) / 256;
  int lo = tid * CH, hi = min(lo + CH, NN);
  int s = 0;
  for (int i = lo; i < hi; i++) s += c[i];
  part[tid] = s;
  __syncthreads();
  if (tid == 0) {
    int run = 0;
    for (int i = 0; i < 256; i++) { int v = part[i]; part[i] = run; run += v; }
  }
  __syncthreads();
  int run = part[tid];
  for (int i = lo; i < hi; i++) { r[i] = run; tm[i] = run; run += c[i]; }
  if (lo < NN && hi == NN) r[NN] = run;
}

__global__ void k_fill(const int* __restrict__ e0, const int* __restrict__ e1,
                       const int* __restrict__ e2, const int* __restrict__ e3,
                       int* __restrict__ tmp, int* __restrict__ col) {
  int i = blockIdx.x * blockDim.x + threadIdx.x;
  if (i >= 4 * EPN) return;
  int t = i / EPN, j = i - t * EPN;
  const int* eb = t == 0 ? e0 : t == 1 ? e1 : t == 2 ? e2 : e3;
  int s, d;
  if (j < NE) { s = eb[j]; d = eb[NE + j]; } else { s = d = j - NE; }
  int pos = atomicAdd(&tmp[t * NN + d], 1);
  col[(size_t)t * EPN + pos] = s;
}

// ---------------- fused GEMM + attention-coefficient epilogue ----------------
// RM rows per thread (BM = RM*16). Thread tile: rows {ra*4+i} (+ {64+ra*4+i} if RM==8),
// cols {tx*4+j, 64+tx*4+j}. Conflict-free LDS: bank = 4(k+idx) mod 32 (2-way, free).
template <int K, int RM>
__global__ __launch_bounds__(256) void k_gemm_attn(
    const float* __restrict__ A, const float* __restrict__ W,
    const float* __restrict__ a_s, const float* __restrict__ a_d,
    float* __restrict__ H, float* __restrict__ asrc, float* __restrict__ adst,
    int colbase, int hstride) {
  constexpr int BM = RM * 16;
  __shared__ float As[32][BM + 4];
  __shared__ float Bs[32][132];
  int tid = threadIdx.x;
  int row0 = blockIdx.x * BM;
  int hcolb = blockIdx.y << 7;
  int gc0 = colbase + hcolb;                 // global fused column (0..1023)
  int t = gc0 >> 8, wc = gc0 & 255;
  const float* WB = W + (size_t)t * K * 256 + wc;
  int tx = tid & 15, ra = tid >> 4;
  float acc[RM][8] = {};

  for (int kb = 0; kb < K; kb += 32) {
    float4 av[RM / 2];
#pragma unroll
    for (int n = 0; n < RM / 2; n++) {
      int idx = tid + n * 256;
      int r = idx >> 3, c4 = (idx & 7) << 2;
      av[n] = make_float4(0.f, 0.f, 0.f, 0.f);
      if (row0 + r < NN) av[n] = *(const float4*)(A + (size_t)(row0 + r) * K + kb + c4);
    }
    float4 bv[4];
#pragma unroll
    for (int n = 0; n < 4; n++) {
      int idx = tid + (n << 8);
      int rb = idx >> 5, c4 = (idx & 31) << 2;
      bv[n] = *(const float4*)(WB + (size_t)(kb + rb) * 256 + c4);
    }
    __syncthreads();
#pragma unroll
    for (int n = 0; n < RM / 2; n++) {
      int idx = tid + n * 256;
      int r = idx >> 3, c4 = (idx & 7) << 2;
      As[c4 + 0][r] = av[n].x; As[c4 + 1][r] = av[n].y;
      As[c4 + 2][r] = av[n].z; As[c4 + 3][r] = av[n].w;
    }
#pragma unroll
    for (int n = 0; n < 4; n++) {
      int idx = tid + (n << 8);
      int rb = idx >> 5, c4 = (idx & 31) << 2;
      *(float4*)&Bs[rb][c4] = bv[n];
    }
    __syncthreads();
#pragma unroll 2
    for (int k = 0; k < 32; k++) {
      float a0[4], a1[4], bb[8];
      *(float4*)a0 = *(const float4*)&As[k][ra << 2];
      if (RM == 8) *(float4*)a1 = *(const float4*)&As[k][64 + (ra << 2)];
      *(float4*)(bb)     = *(const float4*)&Bs[k][tx << 2];
      *(float4*)(bb + 4) = *(const float4*)&Bs[k][64 + (tx << 2)];
#pragma unroll
      for (int i = 0; i < 4; i++)
#pragma unroll
        for (int j = 0; j < 8; j++) {
          acc[i][j] = fmaf(a0[i], bb[j], acc[i][j]);
          if (RM == 8) acc[4 + i][j] = fmaf(a1[i], bb[j], acc[4 + i][j]);
        }
    }
    __syncthreads();
  }

  // epilogue: write H + per-(node,head) attention dots
  float asr[8], adr[8];
#pragma unroll
  for (int j = 0; j < 4; j++) {
    asr[j]     = a_s[gc0 + (tx << 2) + j];
    asr[j + 4] = a_s[gc0 + 64 + (tx << 2) + j];
    adr[j]     = a_d[gc0 + (tx << 2) + j];
    adr[j + 4] = a_d[gc0 + 64 + (tx << 2) + j];
  }
  int slot0 = gc0 >> 6, slot1 = (gc0 + 64) >> 6;
#pragma unroll
  for (int i = 0; i < RM; i++) {
    int lr = (i < 4) ? ((ra << 2) + i) : (64 + (ra << 2) + (i - 4));
    int gr = row0 + lr;
    float ps0 = 0.f, pd0 = 0.f, ps1 = 0.f, pd1 = 0.f;
#pragma unroll
    for (int j = 0; j < 4; j++) {
      ps0 = fmaf(acc[i][j], asr[j], ps0);
      pd0 = fmaf(acc[i][j], adr[j], pd0);
      ps1 = fmaf(acc[i][j + 4], asr[j + 4], ps1);
      pd1 = fmaf(acc[i][j + 4], adr[j + 4], pd1);
    }
#pragma unroll
    for (int m = 1; m < 16; m <<= 1) {
      ps0 += __shfl_xor(ps0, m); pd0 += __shfl_xor(pd0, m);
      ps1 += __shfl_xor(ps1, m); pd1 += __shfl_xor(pd1, m);
    }
    if (gr < NN) {
      *(float4*)(H + (size_t)gr * hstride + hcolb + (tx << 2)) =
          make_float4(acc[i][0], acc[i][1], acc[i][2], acc[i][3]);
      *(float4*)(H + (size_t)gr * hstride + hcolb + 64 + (tx << 2)) =
          make_float4(acc[i][4], acc[i][5], acc[i][6], acc[i][7]);
      if (tx == 0) {
        asrc[(size_t)gr * 16 + slot0] = ps0;
        asrc[(size_t)gr * 16 + slot1] = ps1;
        adst[(size_t)gr * 16 + slot0] = pd0;
        adst[(size_t)gr * 16 + slot1] = pd1;
      }
    }
  }
}

// ---------------- fused aggregation: block = 1 node, wave = 1 edge type ----------------
// Wave-level softmax (shuffle only), float4 gather, head-mean + bias + type-mean + ReLU.
// FINAL: also applies the 64->32 output linear.
template <bool FINAL>
__global__ __launch_bounds__(256) void k_agg_fused(
    const int* __restrict__ rp, const int* __restrict__ col,
    const float* __restrict__ asrc, const float* __restrict__ adst,
    const float* __restrict__ h, const float* __restrict__ bias,
    float* __restrict__ xout, const float* __restrict__ linW,
    const float* __restrict__ linb, int hstride) {
  __shared__ float sbuf[4][64];
  __shared__ float xv[64];
  int v = blockIdx.x;
  int tid = threadIdx.x;
  int t = tid >> 6, lane = tid & 63;
  const int* rpt = rp + t * RP_STRIDE;
  const int* colt = col + (size_t)t * EPN;
  int beg = rpt[v];
  int deg = rpt[v + 1] - beg;
  int slot = (t << 2) + (lane >> 4);
  float adv = adst[(size_t)v * 16 + slot];

  float m = -1e30f;
  for (int i = lane & 15; i < deg; i += 16) {
    int s = colt[beg + i];
    float e = asrc[(size_t)s * 16 + slot] + adv;
    e = e > 0.f ? e : 0.2f * e;
    m = fmaxf(m, e);
  }
  m = fmaxf(m, __shfl_xor(m, 1)); m = fmaxf(m, __shfl_xor(m, 2));
  m = fmaxf(m, __shfl_xor(m, 4)); m = fmaxf(m, __shfl_xor(m, 8));

  float z = 0.f;
  for (int i = lane & 15; i < deg; i += 16) {
    int s = colt[beg + i];
    float e = asrc[(size_t)s * 16 + slot] + adv;
    e = e > 0.f ? e : 0.2f * e;
    z += __expf(e - m);
  }
  z += __shfl_xor(z, 1); z += __shfl_xor(z, 2);
  z += __shfl_xor(z, 4); z += __shfl_xor(z, 8);
  float rz = 1.f / z;

  float f0 = 0.f, f1 = 0.f, f2 = 0.f, f3 = 0.f;
  const float* hb = h + (t << 8) + (lane << 2);
#pragma unroll 2
  for (int i = 0; i < deg; i++) {
    int s = colt[beg + i];
    float e = asrc[(size_t)s * 16 + slot] + adv;
    e = e > 0.f ? e : 0.2f * e;
    float w = __expf(e - m) * rz;
    float4 hv = *(const float4*)(hb + (size_t)s * hstride);
    f0 = fmaf(w, hv.x, f0); f1 = fmaf(w, hv.y, f1);
    f2 = fmaf(w, hv.z, f2); f3 = fmaf(w, hv.w, f3);
  }
  // head mean (sum over the 4 16-lane head groups)
  f0 += __shfl_xor(f0, 16); f0 += __shfl_xor(f0, 32);
  f1 += __shfl_xor(f1, 16); f1 += __shfl_xor(f1, 32);
  f2 += __shfl_xor(f2, 16); f2 += __shfl_xor(f2, 32);
  f3 += __shfl_xor(f3, 16); f3 += __shfl_xor(f3, 32);
  int c = (lane & 15) << 2;
  if (lane < 16) {
    sbuf[t][c + 0] = f0 * 0.25f + bias[(t << 6) + c + 0];
    sbuf[t][c + 1] = f1 * 0.25f + bias[(t << 6) + c + 1];
    sbuf[t][c + 2] = f2 * 0.25f + bias[(t << 6) + c + 2];
    sbuf[t][c + 3] = f3 * 0.25f + bias[(t << 6) + c + 3];
  }
  __syncthreads();
  if (FINAL) {
    if (tid < 64)
      xv[tid] = fmaxf((sbuf[0][tid] + sbuf[1][tid] + sbuf[2][tid] + sbuf[3][tid]) * 0.25f, 0.f);
    __syncthreads();
    if (tid < 32) {
      float accv = linb[tid];
#pragma unroll
      for (int cc = 0; cc < 64; cc++) accv = fmaf(xv[cc], linW[cc * 32 + tid], accv);
      xout[(size_t)v * 32 + tid] = accv;
    }
  } else {
    if (tid < 64)
      xout[(size_t)v * 64 + tid] =
          fmaxf((sbuf[0][tid] + sbuf[1][tid] + sbuf[2][tid] + sbuf[3][tid]) * 0.25f, 0.f);
  }
}

// ---------------- per-type fallback aggregation: wave = 1 node ----------------
__global__ __launch_bounds__(256) void k_agg_pt(
    const int* __restrict__ rp, const int* __restrict__ col,
    const float* __restrict__ asrc, const float* __restrict__ adst,
    const float* __restrict__ h, const float* __restrict__ bias,
    float* __restrict__ accum, int slotbase) {
  int v = blockIdx.x * 4 + (threadIdx.x >> 6);
  int lane = threadIdx.x & 63;
  if (v >= NN) return;
  int slot = slotbase + (lane >> 4);
  int beg = rp[v];
  int deg = rp[v + 1] - beg;
  float adv = adst[(size_t)v * 16 + slot];
  float m = -1e30f;
  for (int i = lane & 15; i < deg; i += 16) {
    int s = col[beg + i];
    float e = asrc[(size_t)s * 16 + slot] + adv;
    e = e > 0.f ? e : 0.2f * e;
    m = fmaxf(m, e);
  }
  m = fmaxf(m, __shfl_xor(m, 1)); m = fmaxf(m, __shfl_xor(m, 2));
  m = fmaxf(m, __shfl_xor(m, 4)); m = fmaxf(m, __shfl_xor(m, 8));
  float z = 0.f;
  for (int i = lane & 15; i < deg; i += 16) {
    int s = col[beg + i];
    float e = asrc[(size_t)s * 16 + slot] + adv;
    e = e > 0.f ? e : 0.2f * e;
    z += __expf(e - m);
  }
  z += __shfl_xor(z, 1); z += __shfl_xor(z, 2);
  z += __shfl_xor(z, 4); z += __shfl_xor(z, 8);
  float rz = 1.f / z;
  float f0 = 0.f, f1 = 0.f, f2 = 0.f, f3 = 0.f;
  const float* hb = h + (lane << 2);
#pragma unroll 2
  for (int i = 0; i < deg; i++) {
    int s = col[beg + i];
    float e = asrc[(size_t)s * 16 + slot] + adv;
    e = e > 0.f ? e : 0.2f * e;
    float w = __expf(e - m) * rz;
    float4 hv = *(const float4*)(hb + (size_t)s * 256);
    f0 = fmaf(w, hv.x, f0); f1 = fmaf(w, hv.y, f1);
    f2 = fmaf(w, hv.z, f2); f3 = fmaf(w, hv.w, f3);
  }
  f0 += __shfl_xor(f0, 16); f0 += __shfl_xor(f0, 32);
  f1 += __shfl_xor(f1, 16); f1 += __shfl_xor(f1, 32);
  f2 += __shfl_xor(f2, 16); f2 += __shfl_xor(f2, 32);
  f3 += __shfl_xor(f3, 16); f3 += __shfl_xor(f3, 32);
  int c = (lane & 15) << 2;
  if (lane < 16) {
    float* ap = accum + (size_t)v * 64 + c;
    ap[0] += f0 * 0.25f + bias[c + 0];
    ap[1] += f1 * 0.25f + bias[c + 1];
    ap[2] += f2 * 0.25f + bias[c + 2];
    ap[3] += f3 * 0.25f + bias[c + 3];
  }
}

__global__ void k_finalize(const float* __restrict__ accum, float* __restrict__ xout) {
  int i = blockIdx.x * blockDim.x + threadIdx.x;
  if (i < NN * NC) xout[i] = fmaxf(accum[i] * 0.25f, 0.f);
}

__global__ void k_linear(const float* __restrict__ x, const float* __restrict__ W,
                         const float* __restrict__ b, float* __restrict__ out) {
  int i = blockIdx.x * blockDim.x + threadIdx.x;
  if (i >= NN * 32) return;
  int v = i >> 5, o = i & 31;
  float acc = b[o];
#pragma unroll
  for (int c = 0; c < 64; c++) acc = fmaf(x[v * 64 + c], W[c * 32 + o], acc);
  out[i] = acc;
}

extern "C" void kernel_launch(void* const* d_in, const int* in_sizes, int n_in,
                              void* d_out, int out_size, void* d_ws, size_t ws_size,
                              hipStream_t stream) {
  const float* x = (const float*)d_in[0];
  const int* e0 = (const int*)d_in[1];
  const int* e1 = (const int*)d_in[2];
  const int* e2 = (const int*)d_in[3];
  const int* e3 = (const int*)d_in[4];
  const float* Wl[2]  = {(const float*)d_in[5], (const float*)d_in[9]};
  const float* asl[2] = {(const float*)d_in[6], (const float*)d_in[10]};
  const float* adl[2] = {(const float*)d_in[7], (const float*)d_in[11]};
  const float* bl[2]  = {(const float*)d_in[8], (const float*)d_in[12]};
  const float* linW = (const float*)d_in[13];
  const float* linb = (const float*)d_in[14];
  float* out = (float*)d_out;
  (void)in_sizes; (void)n_in; (void)out_size;

  bool fused = ws_size >= (size_t)98 * 1024 * 1024;

  char* wsb = (char*)d_ws;
  size_t off = 0;
  auto carve = [&](size_t bytes) -> char* {
    off = (off + 255) & ~(size_t)255;
    char* p = wsb + off;
    off += bytes;
    return p;
  };
  int* cnt    = (int*)carve((size_t)4 * NN * sizeof(int));
  int* tmp    = (int*)carve((size_t)4 * NN * sizeof(int));
  int* rp     = (int*)carve((size_t)4 * RP_STRIDE * sizeof(int));
  int* col    = (int*)carve((size_t)4 * EPN * sizeof(int));
  float* asrc = (float*)carve((size_t)NN * 16 * sizeof(float));
  float* adst = (float*)carve((size_t)NN * 16 * sizeof(float));
  float* h    = (float*)carve((size_t)NN * (fused ? 1024 : 256) * sizeof(float));
  float* xmid = (float*)carve((size_t)NN * NC * sizeof(float));
  float* accum = fused ? nullptr : (float*)carve((size_t)NN * NC * sizeof(float));

  // CSR build (edges identical across layers -> build once per call)
  k_init_counts<<<(4 * NN + 255) / 256, 256, 0, stream>>>(cnt);
  k_count<<<(4 * NE + 255) / 256, 256, 0, stream>>>(e0 + NE, e1 + NE, e2 + NE, e3 + NE, cnt);
  k_scan<<<4, 256, 0, stream>>>(cnt, rp, tmp);
  k_fill<<<(4 * EPN + 255) / 256, 256, 0, stream>>>(e0, e1, e2, e3, tmp, col);

  if (fused) {
    const int GBX = (NN + 127) / 128;
    // layer 0
    k_gemm_attn<128, 8><<<dim3(GBX, 8), 256, 0, stream>>>(
        x, Wl[0], asl[0], adl[0], h, asrc, adst, 0, 1024);
    k_agg_fused<false><<<NN, 256, 0, stream>>>(
        rp, col, asrc, adst, h, bl[0], xmid, nullptr, nullptr, 1024);
    // layer 1 + final linear
    k_gemm_attn<64, 8><<<dim3(GBX, 8), 256, 0, stream>>>(
        xmid, Wl[1], asl[1], adl[1], h, asrc, adst, 0, 1024);
    k_agg_fused<true><<<NN, 256, 0, stream>>>(
        rp, col, asrc, adst, h, bl[1], out, linW, linb, 1024);
  } else {
    const int GBX = (NN + 63) / 64;
    for (int l = 0; l < 2; l++) {
      const float* xin = (l == 0) ? x : xmid;
      hipMemsetAsync(accum, 0, (size_t)NN * NC * sizeof(float), stream);
      for (int t = 0; t < 4; t++) {
        if (l == 0)
          k_gemm_attn<128, 4><<<dim3(GBX, 2), 256, 0, stream>>>(
              xin, Wl[l], asl[l], adl[l], h, asrc, adst, t * 256, 256);
        else
          k_gemm_attn<64, 4><<<dim3(GBX, 2), 256, 0, stream>>>(
              xin, Wl[l], asl[l], adl[l], h, asrc, adst, t * 256, 256);
        k_agg_pt<<<(NN + 3) / 4, 256, 0, stream>>>(
            rp + t * RP_STRIDE, col + (size_t)t * EPN, asrc, adst, h,
            bl[l] + t * NC, accum, t * 4);
      }
      k_finalize<<<(NN * NC + 255) / 256, 256, 0, stream>>>(accum, xmid);
    }
    k_linear<<<(NN * 32 + 255) / 256, 256, 0, stream>>>(xmid, linW, linb, out);
  }
}

// Round 4
// 698.885 us; speedup vs baseline: 3.2136x; 1.0283x over previous
//
#include <hip/hip_runtime.h>

#define NN 20000
#define NE 320000
#define EPN (NE + NN)   // edges + self loops = 340000
#define NH 4
#define NC 64
#define RP_STRIDE 20004
#define DCAP 128        // per-(node,type) degree cap for LDS-cached fast path

// ---------------- CSR build ----------------
__global__ void k_init_counts(int* __restrict__ cnt) {
  int i = blockIdx.x * blockDim.x + threadIdx.x;
  if (i < 4 * NN) cnt[i] = 1;   // self loop
}

__global__ void k_count(const int* __restrict__ d0, const int* __restrict__ d1,
                        const int* __restrict__ d2, const int* __restrict__ d3,
                        int* __restrict__ cnt) {
  int i = blockIdx.x * blockDim.x + threadIdx.x;
  if (i >= 4 * NE) return;
  int t = i / NE, e = i - t * NE;
  const int* d = t == 0 ? d0 : t == 1 ? d1 : t == 2 ? d2 : d3;
  atomicAdd(&cnt[t * NN + d[e]], 1);
}

__global__ void k_scan(const int* __restrict__ cnt, int* __restrict__ rp, int* __restrict__ tmp) {
  int t = blockIdx.x;
  const int* c = cnt + t * NN;
  int* r = rp + t * RP_STRIDE;
  int* tm = tmp + t * NN;
  __shared__ int part[256];
  int tid = threadIdx.x;
  const int CH = (NN + 255) / 256;
  int lo = tid * CH, hi = min(lo + CH, NN);
  int s = 0;
  for (int i = lo; i < hi; i++) s += c[i];
  part[tid] = s;
  __syncthreads();
  if (tid == 0) {
    int run = 0;
    for (int i = 0; i < 256; i++) { int v = part[i]; part[i] = run; run += v; }
  }
  __syncthreads();
  int run = part[tid];
  for (int i = lo; i < hi; i++) { r[i] = run; tm[i] = run; run += c[i]; }
  if (lo < NN && hi == NN) r[NN] = run;
}

__global__ void k_fill(const int* __restrict__ e0, const int* __restrict__ e1,
                       const int* __restrict__ e2, const int* __restrict__ e3,
                       int* __restrict__ tmp, int* __restrict__ col) {
  int i = blockIdx.x * blockDim.x + threadIdx.x;
  if (i >= 4 * EPN) return;
  int t = i / EPN, j = i - t * EPN;
  const int* eb = t == 0 ? e0 : t == 1 ? e1 : t == 2 ? e2 : e3;
  int s, d;
  if (j < NE) { s = eb[j]; d = eb[NE + j]; } else { s = d = j - NE; }
  int pos = atomicAdd(&tmp[t * NN + d], 1);
  col[(size_t)t * EPN + pos] = s;
}

// ---------------- fused GEMM + attention-coefficient epilogue ----------------
// RM rows per thread (BM = RM*16); A-tile double-buffered in registers so the
// HBM load of tile kb+32 overlaps the FMA block of tile kb. B is L2-hot.
template <int K, int RM>
__global__ __launch_bounds__(256) void k_gemm_attn(
    const float* __restrict__ A, const float* __restrict__ W,
    const float* __restrict__ a_s, const float* __restrict__ a_d,
    float* __restrict__ H, float* __restrict__ asrc, float* __restrict__ adst,
    int colbase, int hstride) {
  constexpr int BM = RM * 16;
  __shared__ float As[32][BM + 4];
  __shared__ float Bs[32][132];
  int tid = threadIdx.x;
  int row0 = blockIdx.x * BM;
  int hcolb = blockIdx.y << 7;
  int gc0 = colbase + hcolb;                 // global fused column (0..1023)
  int t = gc0 >> 8, wc = gc0 & 255;
  const float* WB = W + (size_t)t * K * 256 + wc;
  int tx = tid & 15, ra = tid >> 4;
  int kc_a = (tid & 7) << 2;                 // A staging: col within k-tile
  float acc[RM][8] = {};
  float4 av[RM / 2], avn[RM / 2];

  // preload A tile 0
#pragma unroll
  for (int n = 0; n < RM / 2; n++) {
    int r = (tid >> 3) + n * 32;
    av[n] = make_float4(0.f, 0.f, 0.f, 0.f);
    if (row0 + r < NN) av[n] = *(const float4*)(A + (size_t)(row0 + r) * K + kc_a);
  }

#pragma unroll
  for (int kb = 0; kb < K; kb += 32) {
    float4 bv[4];
#pragma unroll
    for (int n = 0; n < 4; n++) {
      int idx = tid + (n << 8);
      int rb = idx >> 5, c4 = (idx & 31) << 2;
      bv[n] = *(const float4*)(WB + (size_t)(kb + rb) * 256 + c4);
    }
    if (kb) __syncthreads();
#pragma unroll
    for (int n = 0; n < RM / 2; n++) {
      int r = (tid >> 3) + n * 32;
      As[kc_a + 0][r] = av[n].x; As[kc_a + 1][r] = av[n].y;
      As[kc_a + 2][r] = av[n].z; As[kc_a + 3][r] = av[n].w;
    }
#pragma unroll
    for (int n = 0; n < 4; n++) {
      int idx = tid + (n << 8);
      int rb = idx >> 5, c4 = (idx & 31) << 2;
      *(float4*)&Bs[rb][c4] = bv[n];
    }
    __syncthreads();
    // prefetch next A tile (overlaps compute below)
    if (kb + 32 < K) {
#pragma unroll
      for (int n = 0; n < RM / 2; n++) {
        int r = (tid >> 3) + n * 32;
        avn[n] = make_float4(0.f, 0.f, 0.f, 0.f);
        if (row0 + r < NN)
          avn[n] = *(const float4*)(A + (size_t)(row0 + r) * K + kb + 32 + kc_a);
      }
    }
#pragma unroll 2
    for (int k = 0; k < 32; k++) {
      float a0[4], a1[4], bb[8];
      *(float4*)a0 = *(const float4*)&As[k][ra << 2];
      if (RM == 8) *(float4*)a1 = *(const float4*)&As[k][64 + (ra << 2)];
      *(float4*)(bb)     = *(const float4*)&Bs[k][tx << 2];
      *(float4*)(bb + 4) = *(const float4*)&Bs[k][64 + (tx << 2)];
#pragma unroll
      for (int i = 0; i < 4; i++)
#pragma unroll
        for (int j = 0; j < 8; j++) {
          acc[i][j] = fmaf(a0[i], bb[j], acc[i][j]);
          if (RM == 8) acc[4 + i][j] = fmaf(a1[i], bb[j], acc[4 + i][j]);
        }
    }
#pragma unroll
    for (int n = 0; n < RM / 2; n++) av[n] = avn[n];
  }

  // epilogue: write H + per-(node,head) attention dots
  float asr[8], adr[8];
#pragma unroll
  for (int j = 0; j < 4; j++) {
    asr[j]     = a_s[gc0 + (tx << 2) + j];
    asr[j + 4] = a_s[gc0 + 64 + (tx << 2) + j];
    adr[j]     = a_d[gc0 + (tx << 2) + j];
    adr[j + 4] = a_d[gc0 + 64 + (tx << 2) + j];
  }
  int slot0 = gc0 >> 6, slot1 = (gc0 + 64) >> 6;
#pragma unroll
  for (int i = 0; i < RM; i++) {
    int lr = (i < 4) ? ((ra << 2) + i) : (64 + (ra << 2) + (i - 4));
    int gr = row0 + lr;
    float ps0 = 0.f, pd0 = 0.f, ps1 = 0.f, pd1 = 0.f;
#pragma unroll
    for (int j = 0; j < 4; j++) {
      ps0 = fmaf(acc[i][j], asr[j], ps0);
      pd0 = fmaf(acc[i][j], adr[j], pd0);
      ps1 = fmaf(acc[i][j + 4], asr[j + 4], ps1);
      pd1 = fmaf(acc[i][j + 4], adr[j + 4], pd1);
    }
#pragma unroll
    for (int m = 1; m < 16; m <<= 1) {
      ps0 += __shfl_xor(ps0, m); pd0 += __shfl_xor(pd0, m);
      ps1 += __shfl_xor(ps1, m); pd1 += __shfl_xor(pd1, m);
    }
    if (gr < NN) {
      *(float4*)(H + (size_t)gr * hstride + hcolb + (tx << 2)) =
          make_float4(acc[i][0], acc[i][1], acc[i][2], acc[i][3]);
      *(float4*)(H + (size_t)gr * hstride + hcolb + 64 + (tx << 2)) =
          make_float4(acc[i][4], acc[i][5], acc[i][6], acc[i][7]);
      if (tx == 0) {
        asrc[(size_t)gr * 16 + slot0] = ps0;
        asrc[(size_t)gr * 16 + slot1] = ps1;
        adst[(size_t)gr * 16 + slot0] = pd0;
        adst[(size_t)gr * 16 + slot1] = pd1;
      }
    }
  }
}

// ---------------- fused aggregation v2: block = 1 node, wave = 1 edge type ----
// Pass A: e computed once per (edge,head) 16-lane-parallel; w=exp(e-m) and the
// col list cached in LDS. Pass B: pure {LDS w + float4 h-gather + fma}, unroll 4.
// 1/z applied once after the loop. Slow recompute path for deg > DCAP.
template <bool FINAL>
__global__ __launch_bounds__(256) void k_agg2(
    const int* __restrict__ rp, const int* __restrict__ col,
    const float* __restrict__ asrc, const float* __restrict__ adst,
    const float* __restrict__ h, const float* __restrict__ bias,
    float* __restrict__ xout, const float* __restrict__ linW,
    const float* __restrict__ linb, int hstride) {
  __shared__ float wl[4][DCAP * 4];
  __shared__ int scol[4][DCAP];
  __shared__ float sbuf[4][64];
  __shared__ float xv[64];
  int v = blockIdx.x;
  int tid = threadIdx.x;
  int t = tid >> 6, lane = tid & 63;
  const int* rpt = rp + t * RP_STRIDE;
  const int* colt = col + (size_t)t * EPN;
  int beg = rpt[v];
  int deg = rpt[v + 1] - beg;
  int hq = lane >> 4, il = lane & 15;
  int slot = (t << 2) + hq;
  float adv = adst[(size_t)v * 16 + slot];
  float f0 = 0.f, f1 = 0.f, f2 = 0.f, f3 = 0.f;
  float rz;
  const float* hb = h + (t << 8) + (lane << 2);

  if (deg <= DCAP) {
    // pass A: e -> LDS, running max
    float m = -1e30f;
    for (int i = il; i < deg; i += 16) {
      int s = colt[beg + i];
      float e = asrc[(size_t)s * 16 + slot] + adv;
      e = e > 0.f ? e : 0.2f * e;
      wl[t][i * 4 + hq] = e;
      if (hq == 0) scol[t][i] = s;
      m = fmaxf(m, e);
    }
    m = fmaxf(m, __shfl_xor(m, 1)); m = fmaxf(m, __shfl_xor(m, 2));
    m = fmaxf(m, __shfl_xor(m, 4)); m = fmaxf(m, __shfl_xor(m, 8));
    // exp pass (LDS-local)
    float z = 0.f;
    for (int i = il; i < deg; i += 16) {
      float w = __expf(wl[t][i * 4 + hq] - m);
      wl[t][i * 4 + hq] = w;
      z += w;
    }
    z += __shfl_xor(z, 1); z += __shfl_xor(z, 2);
    z += __shfl_xor(z, 4); z += __shfl_xor(z, 8);
    rz = 1.f / z;
    // pass B: pure gather + fma
    const float* wlp = &wl[t][hq];
    const int* scp = scol[t];
    int i = 0;
    for (; i + 4 <= deg; i += 4) {
      int s0 = scp[i], s1 = scp[i + 1], s2 = scp[i + 2], s3 = scp[i + 3];
      float4 h0 = *(const float4*)(hb + (size_t)s0 * hstride);
      float4 h1 = *(const float4*)(hb + (size_t)s1 * hstride);
      float4 h2 = *(const float4*)(hb + (size_t)s2 * hstride);
      float4 h3 = *(const float4*)(hb + (size_t)s3 * hstride);
      float w0 = wlp[(i + 0) * 4], w1 = wlp[(i + 1) * 4];
      float w2 = wlp[(i + 2) * 4], w3 = wlp[(i + 3) * 4];
      f0 = fmaf(w0, h0.x, f0); f1 = fmaf(w0, h0.y, f1);
      f2 = fmaf(w0, h0.z, f2); f3 = fmaf(w0, h0.w, f3);
      f0 = fmaf(w1, h1.x, f0); f1 = fmaf(w1, h1.y, f1);
      f2 = fmaf(w1, h1.z, f2); f3 = fmaf(w1, h1.w, f3);
      f0 = fmaf(w2, h2.x, f0); f1 = fmaf(w2, h2.y, f1);
      f2 = fmaf(w2, h2.z, f2); f3 = fmaf(w2, h2.w, f3);
      f0 = fmaf(w3, h3.x, f0); f1 = fmaf(w3, h3.y, f1);
      f2 = fmaf(w3, h3.z, f2); f3 = fmaf(w3, h3.w, f3);
    }
    for (; i < deg; i++) {
      int s = scp[i];
      float w = wlp[i * 4];
      float4 hv = *(const float4*)(hb + (size_t)s * hstride);
      f0 = fmaf(w, hv.x, f0); f1 = fmaf(w, hv.y, f1);
      f2 = fmaf(w, hv.z, f2); f3 = fmaf(w, hv.w, f3);
    }
  } else {
    // slow path: 3-pass recompute (wave-uniform branch, deg unbounded)
    float m = -1e30f;
    for (int i = il; i < deg; i += 16) {
      int s = colt[beg + i];
      float e = asrc[(size_t)s * 16 + slot] + adv;
      e = e > 0.f ? e : 0.2f * e;
      m = fmaxf(m, e);
    }
    m = fmaxf(m, __shfl_xor(m, 1)); m = fmaxf(m, __shfl_xor(m, 2));
    m = fmaxf(m, __shfl_xor(m, 4)); m = fmaxf(m, __shfl_xor(m, 8));
    float z = 0.f;
    for (int i = il; i < deg; i += 16) {
      int s = colt[beg + i];
      float e = asrc[(size_t)s * 16 + slot] + adv;
      e = e > 0.f ? e : 0.2f * e;
      z += __expf(e - m);
    }
    z += __shfl_xor(z, 1); z += __shfl_xor(z, 2);
    z += __shfl_xor(z, 4); z += __shfl_xor(z, 8);
    rz = 1.f / z;
    for (int i = 0; i < deg; i++) {
      int s = colt[beg + i];
      float e = asrc[(size_t)s * 16 + slot] + adv;
      e = e > 0.f ? e : 0.2f * e;
      float w = __expf(e - m);
      float4 hv = *(const float4*)(hb + (size_t)s * hstride);
      f0 = fmaf(w, hv.x, f0); f1 = fmaf(w, hv.y, f1);
      f2 = fmaf(w, hv.z, f2); f3 = fmaf(w, hv.w, f3);
    }
  }
  f0 *= rz; f1 *= rz; f2 *= rz; f3 *= rz;
  // head mean (sum over the 4 16-lane head groups)
  f0 += __shfl_xor(f0, 16); f0 += __shfl_xor(f0, 32);
  f1 += __shfl_xor(f1, 16); f1 += __shfl_xor(f1, 32);
  f2 += __shfl_xor(f2, 16); f2 += __shfl_xor(f2, 32);
  f3 += __shfl_xor(f3, 16); f3 += __shfl_xor(f3, 32);
  int c = il << 2;
  if (lane < 16) {
    sbuf[t][c + 0] = f0 * 0.25f + bias[(t << 6) + c + 0];
    sbuf[t][c + 1] = f1 * 0.25f + bias[(t << 6) + c + 1];
    sbuf[t][c + 2] = f2 * 0.25f + bias[(t << 6) + c + 2];
    sbuf[t][c + 3] = f3 * 0.25f + bias[(t << 6) + c + 3];
  }
  __syncthreads();
  if (FINAL) {
    if (tid < 64)
      xv[tid] = fmaxf((sbuf[0][tid] + sbuf[1][tid] + sbuf[2][tid] + sbuf[3][tid]) * 0.25f, 0.f);
    __syncthreads();
    if (tid < 32) {
      float accv = linb[tid];
#pragma unroll
      for (int cc = 0; cc < 64; cc++) accv = fmaf(xv[cc], linW[cc * 32 + tid], accv);
      xout[(size_t)v * 32 + tid] = accv;
    }
  } else {
    if (tid < 64)
      xout[(size_t)v * 64 + tid] =
          fmaxf((sbuf[0][tid] + sbuf[1][tid] + sbuf[2][tid] + sbuf[3][tid]) * 0.25f, 0.f);
  }
}

// ---------------- per-type fallback aggregation: wave = 1 node ----------------
__global__ __launch_bounds__(256) void k_agg_pt(
    const int* __restrict__ rp, const int* __restrict__ col,
    const float* __restrict__ asrc, const float* __restrict__ adst,
    const float* __restrict__ h, const float* __restrict__ bias,
    float* __restrict__ accum, int slotbase) {
  int v = blockIdx.x * 4 + (threadIdx.x >> 6);
  int lane = threadIdx.x & 63;
  if (v >= NN) return;
  int slot = slotbase + (lane >> 4);
  int beg = rp[v];
  int deg = rp[v + 1] - beg;
  float adv = adst[(size_t)v * 16 + slot];
  float m = -1e30f;
  for (int i = lane & 15; i < deg; i += 16) {
    int s = col[beg + i];
    float e = asrc[(size_t)s * 16 + slot] + adv;
    e = e > 0.f ? e : 0.2f * e;
    m = fmaxf(m, e);
  }
  m = fmaxf(m, __shfl_xor(m, 1)); m = fmaxf(m, __shfl_xor(m, 2));
  m = fmaxf(m, __shfl_xor(m, 4)); m = fmaxf(m, __shfl_xor(m, 8));
  float z = 0.f;
  for (int i = lane & 15; i < deg; i += 16) {
    int s = col[beg + i];
    float e = asrc[(size_t)s * 16 + slot] + adv;
    e = e > 0.f ? e : 0.2f * e;
    z += __expf(e - m);
  }
  z += __shfl_xor(z, 1); z += __shfl_xor(z, 2);
  z += __shfl_xor(z, 4); z += __shfl_xor(z, 8);
  float rz = 1.f / z;
  float f0 = 0.f, f1 = 0.f, f2 = 0.f, f3 = 0.f;
  const float* hb = h + (lane << 2);
#pragma unroll 2
  for (int i = 0; i < deg; i++) {
    int s = col[beg + i];
    float e = asrc[(size_t)s * 16 + slot] + adv;
    e = e > 0.f ? e : 0.2f * e;
    float w = __expf(e - m) * rz;
    float4 hv = *(const float4*)(hb + (size_t)s * 256);
    f0 = fmaf(w, hv.x, f0); f1 = fmaf(w, hv.y, f1);
    f2 = fmaf(w, hv.z, f2); f3 = fmaf(w, hv.w, f3);
  }
  f0 += __shfl_xor(f0, 16); f0 += __shfl_xor(f0, 32);
  f1 += __shfl_xor(f1, 16); f1 += __shfl_xor(f1, 32);
  f2 += __shfl_xor(f2, 16); f2 += __shfl_xor(f2, 32);
  f3 += __shfl_xor(f3, 16); f3 += __shfl_xor(f3, 32);
  int c = (lane & 15) << 2;
  if (lane < 16) {
    float* ap = accum + (size_t)v * 64 + c;
    ap[0] += f0 * 0.25f + bias[c + 0];
    ap[1] += f1 * 0.25f + bias[c + 1];
    ap[2] += f2 * 0.25f + bias[c + 2];
    ap[3] += f3 * 0.25f + bias[c + 3];
  }
}

__global__ void k_finalize(const float* __restrict__ accum, float* __restrict__ xout) {
  int i = blockIdx.x * blockDim.x + threadIdx.x;
  if (i < NN * NC) xout[i] = fmaxf(accum[i] * 0.25f, 0.f);
}

__global__ void k_linear(const float* __restrict__ x, const float* __restrict__ W,
                         const float* __restrict__ b, float* __restrict__ out) {
  int i = blockIdx.x * blockDim.x + threadIdx.x;
  if (i >= NN * 32) return;
  int v = i >> 5, o = i & 31;
  float acc = b[o];
#pragma unroll
  for (int c = 0; c < 64; c++) acc = fmaf(x[v * 64 + c], W[c * 32 + o], acc);
  out[i] = acc;
}

extern "C" void kernel_launch(void* const* d_in, const int* in_sizes, int n_in,
                              void* d_out, int out_size, void* d_ws, size_t ws_size,
                              hipStream_t stream) {
  const float* x = (const float*)d_in[0];
  const int* e0 = (const int*)d_in[1];
  const int* e1 = (const int*)d_in[2];
  const int* e2 = (const int*)d_in[3];
  const int* e3 = (const int*)d_in[4];
  const float* Wl[2]  = {(const float*)d_in[5], (const float*)d_in[9]};
  const float* asl[2] = {(const float*)d_in[6], (const float*)d_in[10]};
  const float* adl[2] = {(const float*)d_in[7], (const float*)d_in[11]};
  const float* bl[2]  = {(const float*)d_in[8], (const float*)d_in[12]};
  const float* linW = (const float*)d_in[13];
  const float* linb = (const float*)d_in[14];
  float* out = (float*)d_out;
  (void)in_sizes; (void)n_in; (void)out_size;

  bool fused = ws_size >= (size_t)98 * 1024 * 1024;

  char* wsb = (char*)d_ws;
  size_t off = 0;
  auto carve = [&](size_t bytes) -> char* {
    off = (off + 255) & ~(size_t)255;
    char* p = wsb + off;
    off += bytes;
    return p;
  };
  int* cnt    = (int*)carve((size_t)4 * NN * sizeof(int));
  int* tmp    = (int*)carve((size_t)4 * NN * sizeof(int));
  int* rp     = (int*)carve((size_t)4 * RP_STRIDE * sizeof(int));
  int* col    = (int*)carve((size_t)4 * EPN * sizeof(int));
  float* asrc = (float*)carve((size_t)NN * 16 * sizeof(float));
  float* adst = (float*)carve((size_t)NN * 16 * sizeof(float));
  float* h    = (float*)carve((size_t)NN * (fused ? 1024 : 256) * sizeof(float));
  float* xmid = (float*)carve((size_t)NN * NC * sizeof(float));
  float* accum = fused ? nullptr : (float*)carve((size_t)NN * NC * sizeof(float));

  // CSR build (edges identical across layers -> build once per call)
  k_init_counts<<<(4 * NN + 255) / 256, 256, 0, stream>>>(cnt);
  k_count<<<(4 * NE + 255) / 256, 256, 0, stream>>>(e0 + NE, e1 + NE, e2 + NE, e3 + NE, cnt);
  k_scan<<<4, 256, 0, stream>>>(cnt, rp, tmp);
  k_fill<<<(4 * EPN + 255) / 256, 256, 0, stream>>>(e0, e1, e2, e3, tmp, col);

  if (fused) {
    const int GBX = (NN + 127) / 128;
    // layer 0
    k_gemm_attn<128, 8><<<dim3(GBX, 8), 256, 0, stream>>>(
        x, Wl[0], asl[0], adl[0], h, asrc, adst, 0, 1024);
    k_agg2<false><<<NN, 256, 0, stream>>>(
        rp, col, asrc, adst, h, bl[0], xmid, nullptr, nullptr, 1024);
    // layer 1 + final linear
    k_gemm_attn<64, 8><<<dim3(GBX, 8), 256, 0, stream>>>(
        xmid, Wl[1], asl[1], adl[1], h, asrc, adst, 0, 1024);
    k_agg2<true><<<NN, 256, 0, stream>>>(
        rp, col, asrc, adst, h, bl[1], out, linW, linb, 1024);
  } else {
    const int GBX = (NN + 63) / 64;
    for (int l = 0; l < 2; l++) {
      const float* xin = (l == 0) ? x : xmid;
      hipMemsetAsync(accum, 0, (size_t)NN * NC * sizeof(float), stream);
      for (int t = 0; t < 4; t++) {
        if (l == 0)
          k_gemm_attn<128, 4><<<dim3(GBX, 2), 256, 0, stream>>>(
              xin, Wl[l], asl[l], adl[l], h, asrc, adst, t * 256, 256);
        else
          k_gemm_attn<64, 4><<<dim3(GBX, 2), 256, 0, stream>>>(
              xin, Wl[l], asl[l], adl[l], h, asrc, adst, t * 256, 256);
        k_agg_pt<<<(NN + 3) / 4, 256, 0, stream>>>(
            rp + t * RP_STRIDE, col + (size_t)t * EPN, asrc, adst, h,
            bl[l] + t * NC, accum, t * 4);
      }
      k_finalize<<<(NN * NC + 255) / 256, 256, 0, stream>>>(accum, xmid);
    }
    k_linear<<<(NN * 32 + 255) / 256, 256, 0, stream>>>(xmid, linW, linb, out);
  }
}